// Round 8
// baseline (181.888 us; speedup 1.0000x reference)
//
#include <hip/hip_runtime.h>

#define NB 16384
#define NC 1000
#define NF 256
#define SE_STRIDE 1004   // halves per g-row in LDS: 2008B row stride, 8B-aligned,
                         // word-stride 502 (mod 32 = 22) -> conflict-free (measured 0)

typedef _Float16 half8 __attribute__((ext_vector_type(8)));
typedef _Float16 half4v __attribute__((ext_vector_type(4)));
typedef float f32x4 __attribute__((ext_vector_type(4)));

// ---- prep: fragment-ordered fp16 means + SoA per-class params ----
// m16f layout: [gt 0..63][kk 0..7][slot 0..63] half8 units where
//   slot s of (gt,kk) = means[min(gt*16+(s&15),999)][kk*32+(s>>4)*8 .. +8]
// Matches the mfma_f32_16x16x32_f16 A-operand lane layout exactly: score's
// per-(tile,kk) means load is ONE coalesced 1024B dwordx4 per wave.
__global__ __launch_bounds__(256) void prep_kernel(
    const float* __restrict__ mean_vecs,
    const float* __restrict__ wb_shape,
    const float* __restrict__ wb_loc,
    const float* __restrict__ wb_scale,
    _Float16* __restrict__ m16f,
    float* __restrict__ pm2,
    float* __restrict__ psh,
    float* __restrict__ pli,
    float* __restrict__ pis)
{
    const int lane = threadIdx.x & 63;
    const int W = blockIdx.x * 4 + (threadIdx.x >> 6);   // grid=252 -> W in [0,1008)

    if (W < 512) {                                       // fragment-order means
        const int gt = W >> 3, kk = W & 7;
        int cls = gt * 16 + (lane & 15);
        if (cls > NC - 1) cls = NC - 1;                  // clamp tail slots
        const float* src = mean_vecs + (size_t)cls * NF + kk * 32 + (lane >> 4) * 8;
        const float4 lo = *(const float4*)src;
        const float4 hi = *(const float4*)(src + 4);
        half8 h;
        h[0]=(_Float16)lo.x; h[1]=(_Float16)lo.y; h[2]=(_Float16)lo.z; h[3]=(_Float16)lo.w;
        h[4]=(_Float16)hi.x; h[5]=(_Float16)hi.y; h[6]=(_Float16)hi.z; h[7]=(_Float16)hi.w;
        *((half8*)m16f + (size_t)W * 64 + lane) = h;     // coalesced 1024B per wave
    }
    if (W < NC) {                                        // per-class params, exact fp32 m2
        const float4 v = *((const float4*)(mean_vecs + (size_t)W * NF) + lane);
        float s = v.x*v.x + v.y*v.y + v.z*v.z + v.w*v.w;
        #pragma unroll
        for (int off = 1; off < 64; off <<= 1) s += __shfl_xor(s, off, 64);
        if (lane == 0) {
            const float isc = 1.0f / wb_scale[W];
            pm2[W] = s;
            psh[W] = wb_shape[W];
            pli[W] = wb_loc[W] * isc;                    // loc/scale
            pis[W] = isc;
        }
    }
}

// ---- single-pass score: 16 rows x all 1000 classes per block ----
// Same structure as r7, with the means prefetch deepened to TWO tiles in
// flight (aA/aB alternating register buffers): tile T's loads are issued two
// tile-bodies (~400-600 cy) before consumption, covering L3 latency (means
// fall out of the stream-churned 4MB L2; 512KB buffer is L3-resident).
__global__ __launch_bounds__(512, 4) void score_kernel(
    const float* __restrict__ logits,
    const float* __restrict__ features,
    const _Float16* __restrict__ m16f,
    const float* __restrict__ pm2,
    const float* __restrict__ psh,
    const float* __restrict__ pli,
    const float* __restrict__ pis,
    float* __restrict__ out)
{
    __shared__ _Float16 se[16][SE_STRIDE];               // 32128 B: g values (fp16)
    __shared__ float sp[4][1024];                        // 16384 B: m2/sh/li/is

    const int lane = threadIdx.x & 63;
    const int wave = threadIdx.x >> 6;
    const int q    = lane >> 4;                          // class sub-group (4 classes)
    const int mr   = lane & 15;                          // row within block's 16-row tile
    const int row  = blockIdx.x * 16 + mr;

    // ---- stage params to LDS (once per block, 16KB, cache-hot) ----
    {
        const int t = threadIdx.x;
        if (t < 256) {
            ((float4*)&sp[0][0])[t] = ((const float4*)pm2)[t];
            ((float4*)&sp[2][0])[t] = ((const float4*)pli)[t];
        } else {
            const int u = t - 256;
            ((float4*)&sp[1][0])[u] = ((const float4*)psh)[u];
            ((float4*)&sp[3][0])[u] = ((const float4*)pis)[u];
        }
    }

    const half8* mbase = (const half8*)m16f + (size_t)(wave * 8) * 8 * 64 + lane;

    // ---- prefetch tiles 0 AND 1 early (2-deep pipeline fill) ----
    half8 aA[8], aB[8];
    #pragma unroll
    for (int kk = 0; kk < 8; ++kk) aA[kk] = mbase[kk * 64];
    #pragma unroll
    for (int kk = 0; kk < 8; ++kk) aB[kk] = mbase[(8 + kk) * 64];

    // ---- B fragments (features for this lane's row) + exact-fp32 f2 ----
    half8 bfrag[8];
    float f2 = 0.f;
    const float* fb = features + (size_t)row * NF;
    #pragma unroll
    for (int kk = 0; kk < 8; ++kk) {
        const float4* p = (const float4*)(fb + kk * 32 + q * 8);
        const float4 lo = p[0], hi = p[1];
        f2 += lo.x*lo.x + lo.y*lo.y + lo.z*lo.z + lo.w*lo.w
            + hi.x*hi.x + hi.y*hi.y + hi.z*hi.z + hi.w*hi.w;
        half8 b;
        b[0]=(_Float16)lo.x; b[1]=(_Float16)lo.y; b[2]=(_Float16)lo.z; b[3]=(_Float16)lo.w;
        b[4]=(_Float16)hi.x; b[5]=(_Float16)hi.y; b[6]=(_Float16)hi.z; b[7]=(_Float16)hi.w;
        bfrag[kk] = b;
    }
    f2 += __shfl_xor(f2, 16, 64);                        // sum the 4 q-chunks (same row)
    f2 += __shfl_xor(f2, 32, 64);

    __syncthreads();                                     // sp staged

    const float LOG2E = 1.44269504088896340736f;
    const float NL2E  = -1.44269504088896340736f;

    // One tile body: MFMA on BUF, refill BUF with tile T+2 (2-deep), Weibull.
    // T is a compile-time constant at every expansion -> all-static indexing.
#define TILE_BODY(T, BUF)                                                     \
    do {                                                                      \
        const int cb   = (wave * 8 + (T)) * 16 + q * 4;                       \
        const bool cvg = (cb <= NC - 4);                                      \
        const int cbc  = cvg ? cb : (NC - 4);                                 \
        f32x4 acc0 = {0.f, 0.f, 0.f, 0.f};                                    \
        f32x4 acc1 = {0.f, 0.f, 0.f, 0.f};                                    \
        _Pragma("unroll")                                                     \
        for (int kk = 0; kk < 4; ++kk) {                                      \
            acc0 = __builtin_amdgcn_mfma_f32_16x16x32_f16(BUF[kk],     bfrag[kk],     acc0, 0, 0, 0); \
            acc1 = __builtin_amdgcn_mfma_f32_16x16x32_f16(BUF[kk + 4], bfrag[kk + 4], acc1, 0, 0, 0); \
        }                                                                     \
        if ((T) + 2 < 8) {                                                    \
            _Pragma("unroll")                                                 \
            for (int kk = 0; kk < 8; ++kk)                                    \
                BUF[kk] = mbase[(size_t)(((T) + 2) * 8 + kk) * 64];           \
        }                                                                     \
        const f32x4 m2v = *(const f32x4*)&sp[0][cbc];                         \
        const f32x4 shv = *(const f32x4*)&sp[1][cbc];                         \
        const f32x4 liv = *(const f32x4*)&sp[2][cbc];                         \
        const f32x4 iv  = *(const f32x4*)&sp[3][cbc];                         \
        half4v oh;                                                            \
        _Pragma("unroll")                                                     \
        for (int j = 0; j < 4; ++j) {                                         \
            float av   = acc0[j] + acc1[j];                                   \
            float d2   = fmaxf(f2 + m2v[j] - 2.0f * av, 1e-12f);              \
            float dist = __builtin_amdgcn_sqrtf(d2);                          \
            float xp   = dist * iv[j] - liv[j];                               \
            float xs   = fmaxf(xp, 1e-30f);                                   \
            float tt   = __builtin_amdgcn_exp2f(                              \
                             shv[j] * __builtin_amdgcn_logf(xs));             \
            float w    = 1.0f - __builtin_amdgcn_exp2f(NL2E * tt);            \
            w = (xp > 0.f) ? w : 0.f;                                         \
            float w2 = w * w, w4 = w2 * w2, w8 = w4 * w4;                     \
            oh[j] = (_Float16)(1.0f - w8 * w2);                               \
        }                                                                     \
        if (cvg)                                                              \
            *(half4v*)&se[mr][cb] = oh;                                       \
    } while (0)

    TILE_BODY(0, aA);
    TILE_BODY(1, aB);
    TILE_BODY(2, aA);
    TILE_BODY(3, aB);
    TILE_BODY(4, aA);
    TILE_BODY(5, aB);
    TILE_BODY(6, aA);
    TILE_BODY(7, aB);
#undef TILE_BODY

    // ---- prefetch phase-2 logits BEFORE the barrier (HBM latency hides);
    //      pre-scale by LOG2E so phase 2 is one mul + one v_exp per element ----
    float4 lgp[2][4];
    #pragma unroll
    for (int rr = 0; rr < 2; ++rr) {
        const size_t grow = (size_t)(blockIdx.x * 16 + wave * 2 + rr);
        const float* lrow = logits + grow * NC;
        #pragma unroll
        for (int i = 0; i < 4; ++i) {
            const int idx = i * 64 + lane;
            if (idx < 250) {
                float4 l4 = *(const float4*)(lrow + idx * 4);
                l4.x *= LOG2E; l4.y *= LOG2E; l4.z *= LOG2E; l4.w *= LOG2E;
                lgp[rr][i] = l4;
            }
        }
    }

    __syncthreads();                                     // all g writes visible

    // ---- phase 2: per wave, 2 complete rows; normalized write, once ----
    #pragma unroll
    for (int rr = 0; rr < 2; ++rr) {
        const int r = wave * 2 + rr;
        const size_t grow = (size_t)(blockIdx.x * 16 + r);

        float4 ev[4];
        float psum = 0.f;
        #pragma unroll
        for (int i = 0; i < 4; ++i) {
            const int idx = i * 64 + lane;               // half4 index within row
            if (idx < 250) {
                const half4v g4 = *(const half4v*)&se[r][idx * 4];
                const float4 l4 = lgp[rr][i];
                float4 e4;
                e4.x = __builtin_amdgcn_exp2f(l4.x * (float)g4[0]);
                e4.y = __builtin_amdgcn_exp2f(l4.y * (float)g4[1]);
                e4.z = __builtin_amdgcn_exp2f(l4.z * (float)g4[2]);
                e4.w = __builtin_amdgcn_exp2f(l4.w * (float)g4[3]);
                ev[i] = e4;
                psum += (e4.x + e4.y) + (e4.z + e4.w);
            }
        }
        #pragma unroll
        for (int off = 1; off < 64; off <<= 1)
            psum += __shfl_xor(psum, off, 64);           // full row sum, all lanes
        const float inv = 1.0f / psum;

        float* orow = out + grow * NC;
        #pragma unroll
        for (int i = 0; i < 4; ++i) {
            const int idx = i * 64 + lane;
            if (idx < 250) {
                float4 v = ev[i];
                v.x *= inv; v.y *= inv; v.z *= inv; v.w *= inv;
                *(float4*)(orow + idx * 4) = v;
            }
        }
    }
}

extern "C" void kernel_launch(void* const* d_in, const int* in_sizes, int n_in,
                              void* d_out, int out_size, void* d_ws, size_t ws_size,
                              hipStream_t stream) {
    const float* logits    = (const float*)d_in[0];
    const float* features  = (const float*)d_in[1];
    const float* mean_vecs = (const float*)d_in[2];
    const float* wb_shape  = (const float*)d_in[3];
    const float* wb_loc    = (const float*)d_in[4];
    const float* wb_scale  = (const float*)d_in[5];
    float* out = (float*)d_out;

    // ws layout: m16f 524288 B | pm2 4096 | psh 4096 | pli 4096 | pis 4096
    _Float16* m16f = (_Float16*)d_ws;
    float* pm2 = (float*)((char*)d_ws + 524288);
    float* psh = (float*)((char*)d_ws + 524288 + 4096);
    float* pli = (float*)((char*)d_ws + 524288 + 8192);
    float* pis = (float*)((char*)d_ws + 524288 + 12288);

    prep_kernel<<<252, 256, 0, stream>>>(mean_vecs, wb_shape, wb_loc, wb_scale,
                                         m16f, pm2, psh, pli, pis);
    score_kernel<<<NB / 16, 512, 0, stream>>>(logits, features, m16f,
                                              pm2, psh, pli, pis, out);
}

// Round 9
// 156.257 us; speedup vs baseline: 1.1640x; 1.1640x over previous
//
#include <hip/hip_runtime.h>

#define NB 16384
#define NC 1000
#define NF 256
#define SE_STRIDE 1004   // halves per g-row in LDS: 2008B row stride, 8B-aligned

typedef _Float16 half8 __attribute__((ext_vector_type(8)));
typedef _Float16 half4v __attribute__((ext_vector_type(4)));
typedef float f32x4 __attribute__((ext_vector_type(4)));

// ---- prep: fragment-ordered fp16 means + SoA per-class params ----
// m16f layout: [gt 0..63][kk 0..7][slot 0..63] half8 units where
//   slot s of (gt,kk) = means[min(gt*16+(s&15),999)][kk*32+(s>>4)*8 .. +8]
// Matches the mfma_f32_16x16x32_f16 A-operand lane layout exactly: score's
// per-(tile,kk) means load is ONE coalesced 1024B dwordx4 per wave.
__global__ __launch_bounds__(256) void prep_kernel(
    const float* __restrict__ mean_vecs,
    const float* __restrict__ wb_shape,
    const float* __restrict__ wb_loc,
    const float* __restrict__ wb_scale,
    _Float16* __restrict__ m16f,
    float* __restrict__ pm2,
    float* __restrict__ psh,
    float* __restrict__ pli,
    float* __restrict__ pis)
{
    const int lane = threadIdx.x & 63;
    const int W = blockIdx.x * 4 + (threadIdx.x >> 6);   // grid=252 -> W in [0,1008)

    if (W < 512) {                                       // fragment-order means
        const int gt = W >> 3, kk = W & 7;
        int cls = gt * 16 + (lane & 15);
        if (cls > NC - 1) cls = NC - 1;                  // clamp tail slots
        const float* src = mean_vecs + (size_t)cls * NF + kk * 32 + (lane >> 4) * 8;
        const float4 lo = *(const float4*)src;
        const float4 hi = *(const float4*)(src + 4);
        half8 h;
        h[0]=(_Float16)lo.x; h[1]=(_Float16)lo.y; h[2]=(_Float16)lo.z; h[3]=(_Float16)lo.w;
        h[4]=(_Float16)hi.x; h[5]=(_Float16)hi.y; h[6]=(_Float16)hi.z; h[7]=(_Float16)hi.w;
        *((half8*)m16f + (size_t)W * 64 + lane) = h;     // coalesced 1024B per wave
    }
    if (W < NC) {                                        // per-class params, exact fp32 m2
        const float4 v = *((const float4*)(mean_vecs + (size_t)W * NF) + lane);
        float s = v.x*v.x + v.y*v.y + v.z*v.z + v.w*v.w;
        #pragma unroll
        for (int off = 1; off < 64; off <<= 1) s += __shfl_xor(s, off, 64);
        if (lane == 0) {
            const float isc = 1.0f / wb_scale[W];
            pm2[W] = s;
            psh[W] = wb_shape[W];
            pli[W] = wb_loc[W] * isc;                    // loc/scale
            pis[W] = isc;
        }
    }
}

// ---- single-pass score: 16 rows x all 1000 classes per block ----
// B (feature) fragments are IDENTICAL across all 8 waves -> staged ONCE in
// 8KB LDS, fragment-linear [kk][lane] so each wave's read is a contiguous
// conflict-free ds_read_b128. This frees 32 VGPRs, which fund a TWO-deep
// means prefetch (aA/aB) without spilling (r8's regression was spill:
// WRITE_SIZE 64->100MB). Tile T's A-loads are now issued two tile-bodies
// (~2x cover) before consumption. Everything else as r7.
__global__ __launch_bounds__(512, 4) void score_kernel(
    const float* __restrict__ logits,
    const float* __restrict__ features,
    const _Float16* __restrict__ m16f,
    const float* __restrict__ pm2,
    const float* __restrict__ psh,
    const float* __restrict__ pli,
    const float* __restrict__ pis,
    float* __restrict__ out)
{
    __shared__ _Float16 sfeat[8][512];                   // 8192 B: B frags [kk][lane*8]
    __shared__ _Float16 se[16][SE_STRIDE];               // 32128 B: g values (fp16)
    __shared__ float sp[4][1024];                        // 16384 B: m2/sh/li/is
    __shared__ float sf2[16];                            // exact-fp32 row norms

    const int lane = threadIdx.x & 63;
    const int wave = threadIdx.x >> 6;
    const int q    = lane >> 4;                          // class sub-group (4 classes)
    const int mr   = lane & 15;                          // row within block's 16-row tile
    const int row  = blockIdx.x * 16 + mr;

    const half8* mbase = (const half8*)m16f + (size_t)(wave * 8) * 8 * 64 + lane;

    // ---- issue 2-deep A prefetch FIRST (tiles 0 and 1) ----
    half8 aA[8], aB[8];
    #pragma unroll
    for (int kk = 0; kk < 8; ++kk) aA[kk] = mbase[kk * 64];
    #pragma unroll
    for (int kk = 0; kk < 8; ++kk) aB[kk] = mbase[(8 + kk) * 64];

    // ---- stage params to LDS (once per block, 16KB, cache-hot) ----
    {
        const int t = threadIdx.x;
        if (t < 256) {
            ((float4*)&sp[0][0])[t] = ((const float4*)pm2)[t];
            ((float4*)&sp[2][0])[t] = ((const float4*)pli)[t];
        } else {
            const int u = t - 256;
            ((float4*)&sp[1][0])[u] = ((const float4*)psh)[u];
            ((float4*)&sp[3][0])[u] = ((const float4*)pis)[u];
        }
    }

    // ---- stage B fragments to LDS once: thread (wave,lane) covers kk=wave,
    //      row=lane&15, chunk=lane>>4; write is contiguous 16B/lane ----
    {
        const float* src = features + (size_t)(blockIdx.x * 16 + mr) * NF
                         + wave * 32 + q * 8;
        const float4 lo = *(const float4*)src;
        const float4 hi = *(const float4*)(src + 4);
        half8 h;
        h[0]=(_Float16)lo.x; h[1]=(_Float16)lo.y; h[2]=(_Float16)lo.z; h[3]=(_Float16)lo.w;
        h[4]=(_Float16)hi.x; h[5]=(_Float16)hi.y; h[6]=(_Float16)hi.z; h[7]=(_Float16)hi.w;
        *(half8*)&sfeat[wave][lane * 8] = h;
    }

    // ---- exact-fp32 f2 per row, computed by wave 0 only ----
    if (wave == 0) {
        float f2l = 0.f;
        const float* fb = features + (size_t)row * NF;
        #pragma unroll
        for (int kk = 0; kk < 8; ++kk) {
            const float4* p = (const float4*)(fb + kk * 32 + q * 8);
            const float4 lo = p[0], hi = p[1];
            f2l += lo.x*lo.x + lo.y*lo.y + lo.z*lo.z + lo.w*lo.w
                 + hi.x*hi.x + hi.y*hi.y + hi.z*hi.z + hi.w*hi.w;
        }
        f2l += __shfl_xor(f2l, 16, 64);
        f2l += __shfl_xor(f2l, 32, 64);
        if (lane < 16) sf2[lane] = f2l;
    }

    __syncthreads();                                     // sp, sfeat, sf2 staged

    const float f2 = sf2[mr];
    const float NL2E = -1.44269504088896340736f;
    const float LOG2E = 1.44269504088896340736f;

    // One tile body: MFMA on BUF (B from LDS), refill BUF with tile T+2,
    // params from LDS, Weibull, g -> se. T is compile-time constant.
#define TILE_BODY(T, BUF)                                                     \
    do {                                                                      \
        const int cb   = (wave * 8 + (T)) * 16 + q * 4;                       \
        const bool cvg = (cb <= NC - 4);                                      \
        const int cbc  = cvg ? cb : (NC - 4);                                 \
        f32x4 acc0 = {0.f, 0.f, 0.f, 0.f};                                    \
        f32x4 acc1 = {0.f, 0.f, 0.f, 0.f};                                    \
        _Pragma("unroll")                                                     \
        for (int kk = 0; kk < 4; ++kk) {                                      \
            const half8 b0 = *(const half8*)&sfeat[kk][lane * 8];             \
            const half8 b1 = *(const half8*)&sfeat[kk + 4][lane * 8];         \
            acc0 = __builtin_amdgcn_mfma_f32_16x16x32_f16(BUF[kk],     b0, acc0, 0, 0, 0); \
            acc1 = __builtin_amdgcn_mfma_f32_16x16x32_f16(BUF[kk + 4], b1, acc1, 0, 0, 0); \
        }                                                                     \
        if ((T) + 2 < 8) {                                                    \
            _Pragma("unroll")                                                 \
            for (int kk = 0; kk < 8; ++kk)                                    \
                BUF[kk] = mbase[(size_t)(((T) + 2) * 8 + kk) * 64];           \
        }                                                                     \
        const f32x4 m2v = *(const f32x4*)&sp[0][cbc];                         \
        const f32x4 shv = *(const f32x4*)&sp[1][cbc];                         \
        const f32x4 liv = *(const f32x4*)&sp[2][cbc];                         \
        const f32x4 iv  = *(const f32x4*)&sp[3][cbc];                         \
        half4v oh;                                                            \
        _Pragma("unroll")                                                     \
        for (int j = 0; j < 4; ++j) {                                         \
            float av   = acc0[j] + acc1[j];                                   \
            float d2   = fmaxf(f2 + m2v[j] - 2.0f * av, 1e-12f);              \
            float dist = __builtin_amdgcn_sqrtf(d2);                          \
            float xp   = dist * iv[j] - liv[j];                               \
            float xs   = fmaxf(xp, 1e-30f);                                   \
            float tt   = __builtin_amdgcn_exp2f(                              \
                             shv[j] * __builtin_amdgcn_logf(xs));             \
            float w    = 1.0f - __builtin_amdgcn_exp2f(NL2E * tt);            \
            w = (xp > 0.f) ? w : 0.f;                                         \
            float w2 = w * w, w4 = w2 * w2, w8 = w4 * w4;                     \
            oh[j] = (_Float16)(1.0f - w8 * w2);                               \
        }                                                                     \
        if (cvg)                                                              \
            *(half4v*)&se[mr][cb] = oh;                                       \
    } while (0)

    TILE_BODY(0, aA);
    TILE_BODY(1, aB);
    TILE_BODY(2, aA);
    TILE_BODY(3, aB);
    TILE_BODY(4, aA);
    TILE_BODY(5, aB);
    TILE_BODY(6, aA);
    TILE_BODY(7, aB);
#undef TILE_BODY

    // ---- prefetch phase-2 logits BEFORE the barrier (HBM latency hides);
    //      pre-scale by LOG2E so phase 2 is one mul + one v_exp per element ----
    float4 lgp[2][4];
    #pragma unroll
    for (int rr = 0; rr < 2; ++rr) {
        const size_t grow = (size_t)(blockIdx.x * 16 + wave * 2 + rr);
        const float* lrow = logits + grow * NC;
        #pragma unroll
        for (int i = 0; i < 4; ++i) {
            const int idx = i * 64 + lane;
            if (idx < 250) {
                float4 l4 = *(const float4*)(lrow + idx * 4);
                l4.x *= LOG2E; l4.y *= LOG2E; l4.z *= LOG2E; l4.w *= LOG2E;
                lgp[rr][i] = l4;
            }
        }
    }

    __syncthreads();                                     // all g writes visible

    // ---- phase 2: per wave, 2 complete rows; normalized write, once ----
    #pragma unroll
    for (int rr = 0; rr < 2; ++rr) {
        const int r = wave * 2 + rr;
        const size_t grow = (size_t)(blockIdx.x * 16 + r);

        float4 ev[4];
        float psum = 0.f;
        #pragma unroll
        for (int i = 0; i < 4; ++i) {
            const int idx = i * 64 + lane;               // half4 index within row
            if (idx < 250) {
                const half4v g4 = *(const half4v*)&se[r][idx * 4];
                const float4 l4 = lgp[rr][i];
                float4 e4;
                e4.x = __builtin_amdgcn_exp2f(l4.x * (float)g4[0]);
                e4.y = __builtin_amdgcn_exp2f(l4.y * (float)g4[1]);
                e4.z = __builtin_amdgcn_exp2f(l4.z * (float)g4[2]);
                e4.w = __builtin_amdgcn_exp2f(l4.w * (float)g4[3]);
                ev[i] = e4;
                psum += (e4.x + e4.y) + (e4.z + e4.w);
            }
        }
        #pragma unroll
        for (int off = 1; off < 64; off <<= 1)
            psum += __shfl_xor(psum, off, 64);           // full row sum, all lanes
        const float inv = 1.0f / psum;

        float* orow = out + grow * NC;
        #pragma unroll
        for (int i = 0; i < 4; ++i) {
            const int idx = i * 64 + lane;
            if (idx < 250) {
                float4 v = ev[i];
                v.x *= inv; v.y *= inv; v.z *= inv; v.w *= inv;
                *(float4*)(orow + idx * 4) = v;
            }
        }
    }
}

extern "C" void kernel_launch(void* const* d_in, const int* in_sizes, int n_in,
                              void* d_out, int out_size, void* d_ws, size_t ws_size,
                              hipStream_t stream) {
    const float* logits    = (const float*)d_in[0];
    const float* features  = (const float*)d_in[1];
    const float* mean_vecs = (const float*)d_in[2];
    const float* wb_shape  = (const float*)d_in[3];
    const float* wb_loc    = (const float*)d_in[4];
    const float* wb_scale  = (const float*)d_in[5];
    float* out = (float*)d_out;

    // ws layout: m16f 524288 B | pm2 4096 | psh 4096 | pli 4096 | pis 4096
    _Float16* m16f = (_Float16*)d_ws;
    float* pm2 = (float*)((char*)d_ws + 524288);
    float* psh = (float*)((char*)d_ws + 524288 + 4096);
    float* pli = (float*)((char*)d_ws + 524288 + 8192);
    float* pis = (float*)((char*)d_ws + 524288 + 12288);

    prep_kernel<<<252, 256, 0, stream>>>(mean_vecs, wb_shape, wb_loc, wb_scale,
                                         m16f, pm2, psh, pli, pis);
    score_kernel<<<NB / 16, 512, 0, stream>>>(logits, features, m16f,
                                              pm2, psh, pli, pis, out);
}

// Round 10
// 151.671 us; speedup vs baseline: 1.1992x; 1.0302x over previous
//
#include <hip/hip_runtime.h>

#define NB 16384
#define NC 1000
#define NF 256
#define SE_STRIDE 1004   // halves per g-row in LDS: 2008B row stride, 8B-aligned

typedef _Float16 half8 __attribute__((ext_vector_type(8)));
typedef _Float16 half4v __attribute__((ext_vector_type(4)));
typedef float f32x4 __attribute__((ext_vector_type(4)));

// ---- prep: fragment-ordered fp16 means + SoA per-class params ----
// m16f layout: [gt 0..63][kk 0..7][slot 0..63] half8 units where
//   slot s of (gt,kk) = means[min(gt*16+(s&15),999)][kk*32+(s>>4)*8 .. +8]
// Matches the mfma_f32_16x16x32_f16 A-operand lane layout exactly: score's
// per-(tile,kk) means load is ONE coalesced 1024B dwordx4 per wave.
__global__ __launch_bounds__(256) void prep_kernel(
    const float* __restrict__ mean_vecs,
    const float* __restrict__ wb_shape,
    const float* __restrict__ wb_loc,
    const float* __restrict__ wb_scale,
    _Float16* __restrict__ m16f,
    float* __restrict__ pm2,
    float* __restrict__ psh,
    float* __restrict__ pli,
    float* __restrict__ pis)
{
    const int lane = threadIdx.x & 63;
    const int W = blockIdx.x * 4 + (threadIdx.x >> 6);   // grid=252 -> W in [0,1008)

    if (W < 512) {                                       // fragment-order means
        const int gt = W >> 3, kk = W & 7;
        int cls = gt * 16 + (lane & 15);
        if (cls > NC - 1) cls = NC - 1;                  // clamp tail slots
        const float* src = mean_vecs + (size_t)cls * NF + kk * 32 + (lane >> 4) * 8;
        const float4 lo = *(const float4*)src;
        const float4 hi = *(const float4*)(src + 4);
        half8 h;
        h[0]=(_Float16)lo.x; h[1]=(_Float16)lo.y; h[2]=(_Float16)lo.z; h[3]=(_Float16)lo.w;
        h[4]=(_Float16)hi.x; h[5]=(_Float16)hi.y; h[6]=(_Float16)hi.z; h[7]=(_Float16)hi.w;
        *((half8*)m16f + (size_t)W * 64 + lane) = h;     // coalesced 1024B per wave
    }
    if (W < NC) {                                        // per-class params, exact fp32 m2
        const float4 v = *((const float4*)(mean_vecs + (size_t)W * NF) + lane);
        float s = v.x*v.x + v.y*v.y + v.z*v.z + v.w*v.w;
        #pragma unroll
        for (int off = 1; off < 64; off <<= 1) s += __shfl_xor(s, off, 64);
        if (lane == 0) {
            const float isc = 1.0f / wb_scale[W];
            pm2[W] = s;
            psh[W] = wb_shape[W];
            pli[W] = wb_loc[W] * isc;                    // loc/scale
            pis[W] = isc;
        }
    }
}

// ---- single-pass score: 16 rows x all 1000 classes per block ----
// r9 structure (B frags staged once in LDS; 2-deep means prefetch aA/aB;
// params in LDS; fp16 g buffer; in-block softmax; single normalized write)
// plus: (1) f2 preamble parallelized across 4 waves (was wave-0-serial --
// cold-run critical path), (2) s_setprio(1) around the MFMA cluster (waves
// are phase-diverse here; T5 regime), (3) nontemporal `out` stores (65MB
// write-once stream was churning the 4MB/XCD L2, evicting hot means/params).
__global__ __launch_bounds__(512, 4) void score_kernel(
    const float* __restrict__ logits,
    const float* __restrict__ features,
    const _Float16* __restrict__ m16f,
    const float* __restrict__ pm2,
    const float* __restrict__ psh,
    const float* __restrict__ pli,
    const float* __restrict__ pis,
    float* __restrict__ out)
{
    __shared__ _Float16 sfeat[8][512];                   // 8192 B: B frags [kk][lane*8]
    __shared__ _Float16 se[16][SE_STRIDE];               // 32128 B: g values (fp16)
    __shared__ float sp[4][1024];                        // 16384 B: m2/sh/li/is
    __shared__ float sf2[16];                            // exact-fp32 row norms

    const int lane = threadIdx.x & 63;
    const int wave = threadIdx.x >> 6;
    const int q    = lane >> 4;                          // class sub-group (4 classes)
    const int mr   = lane & 15;                          // row within block's 16-row tile

    const half8* mbase = (const half8*)m16f + (size_t)(wave * 8) * 8 * 64 + lane;

    // ---- issue 2-deep A prefetch FIRST (tiles 0 and 1) ----
    half8 aA[8], aB[8];
    #pragma unroll
    for (int kk = 0; kk < 8; ++kk) aA[kk] = mbase[kk * 64];
    #pragma unroll
    for (int kk = 0; kk < 8; ++kk) aB[kk] = mbase[(8 + kk) * 64];

    // ---- stage params to LDS (once per block, 16KB, cache-hot) ----
    {
        const int t = threadIdx.x;
        if (t < 256) {
            ((float4*)&sp[0][0])[t] = ((const float4*)pm2)[t];
            ((float4*)&sp[2][0])[t] = ((const float4*)pli)[t];
        } else {
            const int u = t - 256;
            ((float4*)&sp[1][0])[u] = ((const float4*)psh)[u];
            ((float4*)&sp[3][0])[u] = ((const float4*)pis)[u];
        }
    }

    // ---- stage B fragments to LDS once: thread (wave,lane) covers kk=wave,
    //      row=lane&15, chunk=lane>>4; write is contiguous 16B/lane ----
    {
        const float* src = features + (size_t)(blockIdx.x * 16 + mr) * NF
                         + wave * 32 + q * 8;
        const float4 lo = *(const float4*)src;
        const float4 hi = *(const float4*)(src + 4);
        half8 h;
        h[0]=(_Float16)lo.x; h[1]=(_Float16)lo.y; h[2]=(_Float16)lo.z; h[3]=(_Float16)lo.w;
        h[4]=(_Float16)hi.x; h[5]=(_Float16)hi.y; h[6]=(_Float16)hi.z; h[7]=(_Float16)hi.w;
        *(half8*)&sfeat[wave][lane * 8] = h;
    }

    // ---- exact-fp32 f2 per row, 4 waves x 4 rows (parallel preamble) ----
    if (wave < 4) {
        const int r   = wave * 4 + (lane >> 4);          // this lane's row
        const int c16 = lane & 15;                       // 16 lanes per row
        const float4* fb = (const float4*)(features
                          + (size_t)(blockIdx.x * 16 + r) * NF) + c16 * 4;
        float s = 0.f;
        #pragma unroll
        for (int i = 0; i < 4; ++i) {
            const float4 v = fb[i];
            s += v.x*v.x + v.y*v.y + v.z*v.z + v.w*v.w;
        }
        s += __shfl_xor(s, 1, 64);                       // reduce within 16-lane group
        s += __shfl_xor(s, 2, 64);
        s += __shfl_xor(s, 4, 64);
        s += __shfl_xor(s, 8, 64);
        if (c16 == 0) sf2[r] = s;
    }

    __syncthreads();                                     // sp, sfeat, sf2 staged

    const float f2 = sf2[mr];
    const float NL2E = -1.44269504088896340736f;
    const float LOG2E = 1.44269504088896340736f;

    // One tile body: MFMA on BUF (B from LDS), refill BUF with tile T+2,
    // params from LDS, Weibull, g -> se. T is compile-time constant.
#define TILE_BODY(T, BUF)                                                     \
    do {                                                                      \
        const int cb   = (wave * 8 + (T)) * 16 + q * 4;                       \
        const bool cvg = (cb <= NC - 4);                                      \
        const int cbc  = cvg ? cb : (NC - 4);                                 \
        f32x4 acc0 = {0.f, 0.f, 0.f, 0.f};                                    \
        f32x4 acc1 = {0.f, 0.f, 0.f, 0.f};                                    \
        __builtin_amdgcn_s_setprio(1);                                        \
        _Pragma("unroll")                                                     \
        for (int kk = 0; kk < 4; ++kk) {                                      \
            const half8 b0 = *(const half8*)&sfeat[kk][lane * 8];             \
            const half8 b1 = *(const half8*)&sfeat[kk + 4][lane * 8];         \
            acc0 = __builtin_amdgcn_mfma_f32_16x16x32_f16(BUF[kk],     b0, acc0, 0, 0, 0); \
            acc1 = __builtin_amdgcn_mfma_f32_16x16x32_f16(BUF[kk + 4], b1, acc1, 0, 0, 0); \
        }                                                                     \
        __builtin_amdgcn_s_setprio(0);                                        \
        if ((T) + 2 < 8) {                                                    \
            _Pragma("unroll")                                                 \
            for (int kk = 0; kk < 8; ++kk)                                    \
                BUF[kk] = mbase[(size_t)(((T) + 2) * 8 + kk) * 64];           \
        }                                                                     \
        const f32x4 m2v = *(const f32x4*)&sp[0][cbc];                         \
        const f32x4 shv = *(const f32x4*)&sp[1][cbc];                         \
        const f32x4 liv = *(const f32x4*)&sp[2][cbc];                         \
        const f32x4 iv  = *(const f32x4*)&sp[3][cbc];                         \
        half4v oh;                                                            \
        _Pragma("unroll")                                                     \
        for (int j = 0; j < 4; ++j) {                                         \
            float av   = acc0[j] + acc1[j];                                   \
            float d2   = fmaxf(f2 + m2v[j] - 2.0f * av, 1e-12f);              \
            float dist = __builtin_amdgcn_sqrtf(d2);                          \
            float xp   = dist * iv[j] - liv[j];                               \
            float xs   = fmaxf(xp, 1e-30f);                                   \
            float tt   = __builtin_amdgcn_exp2f(                              \
                             shv[j] * __builtin_amdgcn_logf(xs));             \
            float w    = 1.0f - __builtin_amdgcn_exp2f(NL2E * tt);            \
            w = (xp > 0.f) ? w : 0.f;                                         \
            float w2 = w * w, w4 = w2 * w2, w8 = w4 * w4;                     \
            oh[j] = (_Float16)(1.0f - w8 * w2);                               \
        }                                                                     \
        if (cvg)                                                              \
            *(half4v*)&se[mr][cb] = oh;                                       \
    } while (0)

    TILE_BODY(0, aA);
    TILE_BODY(1, aB);
    TILE_BODY(2, aA);
    TILE_BODY(3, aB);
    TILE_BODY(4, aA);
    TILE_BODY(5, aB);
    TILE_BODY(6, aA);
    TILE_BODY(7, aB);
#undef TILE_BODY

    // ---- prefetch phase-2 logits BEFORE the barrier (HBM latency hides);
    //      pre-scale by LOG2E so phase 2 is one mul + one v_exp per element ----
    float4 lgp[2][4];
    #pragma unroll
    for (int rr = 0; rr < 2; ++rr) {
        const size_t grow = (size_t)(blockIdx.x * 16 + wave * 2 + rr);
        const float* lrow = logits + grow * NC;
        #pragma unroll
        for (int i = 0; i < 4; ++i) {
            const int idx = i * 64 + lane;
            if (idx < 250) {
                float4 l4 = *(const float4*)(lrow + idx * 4);
                l4.x *= LOG2E; l4.y *= LOG2E; l4.z *= LOG2E; l4.w *= LOG2E;
                lgp[rr][i] = l4;
            }
        }
    }

    __syncthreads();                                     // all g writes visible

    // ---- phase 2: per wave, 2 complete rows; normalized NT write, once ----
    #pragma unroll
    for (int rr = 0; rr < 2; ++rr) {
        const int r = wave * 2 + rr;
        const size_t grow = (size_t)(blockIdx.x * 16 + r);

        float4 ev[4];
        float psum = 0.f;
        #pragma unroll
        for (int i = 0; i < 4; ++i) {
            const int idx = i * 64 + lane;               // half4 index within row
            if (idx < 250) {
                const half4v g4 = *(const half4v*)&se[r][idx * 4];
                const float4 l4 = lgp[rr][i];
                float4 e4;
                e4.x = __builtin_amdgcn_exp2f(l4.x * (float)g4[0]);
                e4.y = __builtin_amdgcn_exp2f(l4.y * (float)g4[1]);
                e4.z = __builtin_amdgcn_exp2f(l4.z * (float)g4[2]);
                e4.w = __builtin_amdgcn_exp2f(l4.w * (float)g4[3]);
                ev[i] = e4;
                psum += (e4.x + e4.y) + (e4.z + e4.w);
            }
        }
        #pragma unroll
        for (int off = 1; off < 64; off <<= 1)
            psum += __shfl_xor(psum, off, 64);           // full row sum, all lanes
        const float inv = 1.0f / psum;

        float* orow = out + grow * NC;
        #pragma unroll
        for (int i = 0; i < 4; ++i) {
            const int idx = i * 64 + lane;
            if (idx < 250) {
                f32x4 sv;
                sv[0] = ev[i].x * inv; sv[1] = ev[i].y * inv;
                sv[2] = ev[i].z * inv; sv[3] = ev[i].w * inv;
                __builtin_nontemporal_store(sv, (f32x4*)(orow + idx * 4));
            }
        }
    }
}

extern "C" void kernel_launch(void* const* d_in, const int* in_sizes, int n_in,
                              void* d_out, int out_size, void* d_ws, size_t ws_size,
                              hipStream_t stream) {
    const float* logits    = (const float*)d_in[0];
    const float* features  = (const float*)d_in[1];
    const float* mean_vecs = (const float*)d_in[2];
    const float* wb_shape  = (const float*)d_in[3];
    const float* wb_loc    = (const float*)d_in[4];
    const float* wb_scale  = (const float*)d_in[5];
    float* out = (float*)d_out;

    // ws layout: m16f 524288 B | pm2 4096 | psh 4096 | pli 4096 | pis 4096
    _Float16* m16f = (_Float16*)d_ws;
    float* pm2 = (float*)((char*)d_ws + 524288);
    float* psh = (float*)((char*)d_ws + 524288 + 4096);
    float* pli = (float*)((char*)d_ws + 524288 + 8192);
    float* pis = (float*)((char*)d_ws + 524288 + 12288);

    prep_kernel<<<252, 256, 0, stream>>>(mean_vecs, wb_shape, wb_loc, wb_scale,
                                         m16f, pm2, psh, pli, pis);
    score_kernel<<<NB / 16, 512, 0, stream>>>(logits, features, m16f,
                                              pm2, psh, pli, pis, out);
}